// Round 1
// baseline (710.889 us; speedup 1.0000x reference)
//
#include <hip/hip_runtime.h>
#include <hip/hip_bf16.h>

#define N_POINTS   262144
#define D_EMBED    512
#define N_CLUSTERS 64
#define LAMBD      0.1f

#define THREADS      512
#define PTS_PER_BLK  256
#define PTS_PER_WAVE 32
#define KC           64                  // floats per K-chunk
#define NCHUNK       (D_EMBED / KC)      // 8

typedef __attribute__((ext_vector_type(8)))  short short8;   // 8 bf16 (4 VGPRs)
typedef __attribute__((ext_vector_type(16))) float f32x16;   // 32x32 MFMA C/D

__device__ __forceinline__ unsigned short f2bf(float f) {
    union { float f; unsigned u; } v; v.f = f;
    unsigned u = v.u;
    return (unsigned short)((u + 0x7FFFu + ((u >> 16) & 1u)) >> 16);  // RNE
}

// ---------------------------------------------------------------------------
// Prep: c2[k]; centroid A-fragments for v_mfma_f32_32x32x16_bf16.
// A layout (m = lane&31, k = 8*(lane>>5)+j):
//   afrag[((s*2 + t)*64 + m + 32*h)*8 + j] = bf16(cent[32t + m][16s + 8h + j])
// One block per cluster k; lane covers d = 8*lane .. 8*lane+7
//   -> s = lane>>1, h = lane&1, j = 0..7.   (unchanged from previous version)
// ---------------------------------------------------------------------------
__global__ void prep_kernel(const float* __restrict__ cent,
                            float* __restrict__ c2_ws,
                            unsigned short* __restrict__ afrag,
                            float* __restrict__ out) {
    const int k    = blockIdx.x;
    const int lane = threadIdx.x;
    const float* row = cent + (size_t)k * D_EMBED;

    float4 v0 = ((const float4*)row)[lane * 2 + 0];
    float4 v1 = ((const float4*)row)[lane * 2 + 1];

    float s = v0.x*v0.x + v0.y*v0.y + v0.z*v0.z + v0.w*v0.w
            + v1.x*v1.x + v1.y*v1.y + v1.z*v1.z + v1.w*v1.w;
    #pragma unroll
    for (int m = 1; m < 64; m <<= 1) s += __shfl_xor(s, m);
    if (lane == 0) c2_ws[k] = s;

    const int st = lane >> 1;      // K-step (of 16)
    const int h  = lane & 1;       // k-half within step
    const int t  = k >> 5;         // cluster tile
    const int m  = k & 31;         // cluster within tile
    const size_t idx8 = ((size_t)(st * 2 + t) * 64 + m + 32 * h) * 8;

    ushort4 h0, h1;
    h0.x = f2bf(v0.x); h0.y = f2bf(v0.y); h0.z = f2bf(v0.z); h0.w = f2bf(v0.w);
    h1.x = f2bf(v1.x); h1.y = f2bf(v1.y); h1.z = f2bf(v1.z); h1.w = f2bf(v1.w);
    *(ushort4*)&afrag[idx8 + 0] = h0;
    *(ushort4*)&afrag[idx8 + 4] = h1;

    if (k == 0 && lane == 0) *out = 0.0f;   // d_out poisoned 0xAA every call
}

// ---------------------------------------------------------------------------
// Main, v2: COALESCED x streaming.
//   The old kernel read x per-lane (64 lanes x 16 B over 32 rows 2 KiB apart
//   per instruction) -> ~32 scattered line-requests per load, starving the
//   per-CU outstanding-request budget -> ~1.6 TB/s. Now threads load
//   block-contiguous float4s (8 KiB contiguous per issue round), convert to
//   bf16 + accumulate x2 at stage time, and park chunks in LDS (XOR-swizzled
//   so the consumer's b-frag is ONE ds_read_b128 at <=4-way conflict).
//
//   LDS: afrag 64 KiB + x dbuf 2x32 KiB + x2a 1 KiB + c2s + bsum = 129.3 KiB
//        -> 1 block/CU, 8 waves/CU (same wave count as before).
//   Staging granule map: fp32 granule f = tid + 512*i  (i = 0..7)
//        pt = (tid>>4) + 32*i, gf = tid&15   (pt&7 is i-invariant)
//        bf16 slot (shorts) = pt*64 + ((gf>>1) ^ (pt&7))*8 + (gf&1)*4
//   Consumer (wave w, lane l: n=l&31, h=l>>5, pl=32w+n), step s in chunk:
//        b-frag shorts = pl*64 + ((2s+h) ^ (pl&7))*8       (one b128)
// ---------------------------------------------------------------------------
__global__ __launch_bounds__(THREADS, 2)
void main_kernel(const float* __restrict__ x,
                 const int* __restrict__ alpha_p,
                 const float* __restrict__ c2_ws,
                 const unsigned short* __restrict__ afrag,
                 float* __restrict__ out) {
    __shared__ unsigned short alds[64 * 64 * 8];          // 64 KiB A-fragments
    __shared__ unsigned short xb[2][PTS_PER_BLK * KC];    // 2 x 32 KiB bf16 x
    __shared__ float x2a[PTS_PER_BLK];
    __shared__ float c2s[N_CLUSTERS];
    __shared__ float bsum[8];

    const int tid  = threadIdx.x;
    const int lane = tid & 63;
    const int w    = tid >> 6;

    // ---- stage all A-fragments to LDS (64 KiB, coalesced)
    #pragma unroll
    for (int it = 0; it < 8; ++it) {
        const int e8 = it * THREADS + tid;                // 16B chunk index
        *(short8*)&alds[(size_t)e8 * 8] = *(const short8*)&afrag[(size_t)e8 * 8];
    }
    if (tid < 64) c2s[tid] = c2_ws[tid];

    // ---- staging geometry (perfectly coalesced global reads)
    const int pt0 = tid >> 4;                             // + 32*i
    const int gf  = tid & 15;                             // fp32 16B granule
    const char* src0 = (const char*)x
        + (size_t)blockIdx.x * PTS_PER_BLK * (D_EMBED * 4)
        + (size_t)pt0 * (D_EMBED * 4) + gf * 16;
    const int soff = pt0 * KC + (((gf >> 1) ^ (pt0 & 7)) * 8) + (gf & 1) * 4;

    // ---- consumer geometry
    const float alpha = (float)alpha_p[0];
    const int n    = lane & 31;        // point within wave / C/D col
    const int h    = lane >> 5;        // k-half
    const int pl   = w * PTS_PER_WAVE + n;   // local point 0..255
    const int xrow = pl * KC;                // shorts
    const int xswz = pl & 7;

    f32x16 acc0, acc1;
    #pragma unroll
    for (int q = 0; q < 16; ++q) { acc0[q] = 0.0f; acc1[q] = 0.0f; }

    float4 r[8];
    float  x2p[8];
    #pragma unroll
    for (int i = 0; i < 8; ++i) x2p[i] = 0.0f;

    // ---- prologue: load + convert chunk 0
    #pragma unroll
    for (int i = 0; i < 8; ++i)
        r[i] = *(const float4*)(src0 + (size_t)i * (32 * D_EMBED * 4));
    __syncthreads();                       // alds, c2s ready
    #pragma unroll
    for (int i = 0; i < 8; ++i) {
        const float4 u = r[i];
        x2p[i] += u.x*u.x + u.y*u.y + u.z*u.z + u.w*u.w;
        ushort4 hv;
        hv.x = f2bf(u.x); hv.y = f2bf(u.y); hv.z = f2bf(u.z); hv.w = f2bf(u.w);
        *(ushort4*)&xb[0][soff + i * (32 * KC)] = hv;
    }
    __syncthreads();                       // xb[0] ready

    // ---- K-loop: 8 chunks, double-buffered, loads issued before MFMA phase
    int cur = 0;
    #pragma unroll
    for (int c = 0; c < NCHUNK; ++c) {
        if (c + 1 < NCHUNK) {
            #pragma unroll
            for (int i = 0; i < 8; ++i)
                r[i] = *(const float4*)(src0 + (size_t)i * (32 * D_EMBED * 4)
                                             + (size_t)(c + 1) * (KC * 4));
        }
        // compute 4 K-steps (K=16 each) on xb[cur]
        #pragma unroll
        for (int s = 0; s < 4; ++s) {
            const int S = c * 4 + s;       // global K-step 0..31
            const short8 b  = *(const short8*)&xb[cur][xrow + (((2 * s + h) ^ xswz) * 8)];
            const short8 a0 = *(const short8*)&alds[((size_t)(S * 2 + 0) * 64 + lane) * 8];
            const short8 a1 = *(const short8*)&alds[((size_t)(S * 2 + 1) * 64 + lane) * 8];
            acc0 = __builtin_amdgcn_mfma_f32_32x32x16_bf16(a0, b, acc0, 0, 0, 0);
            acc1 = __builtin_amdgcn_mfma_f32_32x32x16_bf16(a1, b, acc1, 0, 0, 0);
        }
        // convert + write chunk c+1 into the other buffer (waits its loads)
        if (c + 1 < NCHUNK) {
            #pragma unroll
            for (int i = 0; i < 8; ++i) {
                const float4 u = r[i];
                x2p[i] += u.x*u.x + u.y*u.y + u.z*u.z + u.w*u.w;
                ushort4 hv;
                hv.x = f2bf(u.x); hv.y = f2bf(u.y); hv.z = f2bf(u.z); hv.w = f2bf(u.w);
                *(ushort4*)&xb[cur ^ 1][soff + i * (32 * KC)] = hv;
            }
        }
        __syncthreads();
        cur ^= 1;
    }

    // ---- x2 finalize: 16-lane groups share a point; leaders store (fp32-exact)
    #pragma unroll
    for (int i = 0; i < 8; ++i) {
        float v = x2p[i];
        v += __shfl_xor(v, 1);
        v += __shfl_xor(v, 2);
        v += __shfl_xor(v, 4);
        v += __shfl_xor(v, 8);
        if ((tid & 15) == 0) x2a[pt0 + 32 * i] = v;
    }
    __syncthreads();
    const float x2 = x2a[pl];

    // dist in place of acc; C/D: col = lane&31 = point, row = (q&3)+8*(q>>2)+4*h
    float minv = 1e30f;
    #pragma unroll
    for (int q = 0; q < 16; ++q) {
        const int rr = (q & 3) + 8 * (q >> 2) + 4 * h;
        const float d0 = x2 + c2s[rr]      - 2.0f * acc0[q];
        const float d1 = x2 + c2s[rr + 32] - 2.0f * acc1[q];
        acc0[q] = d0; acc1[q] = d1;
        minv = fminf(minv, fminf(d0, d1));
    }
    minv = fminf(minv, __shfl_xor(minv, 32));

    float esum = 0.0f, wsum = 0.0f;
    #pragma unroll
    for (int q = 0; q < 16; ++q) {
        const float e0 = __expf(-alpha * (acc0[q] - minv));
        const float e1 = __expf(-alpha * (acc1[q] - minv));
        esum += e0 + e1;
        wsum += acc0[q] * e0 + acc1[q] * e1;
    }
    esum += __shfl_xor(esum, 32);
    wsum += __shfl_xor(wsum, 32);

    float pv = wsum / esum;                 // per-point value, 2 copies/point
    #pragma unroll
    for (int m = 1; m < 64; m <<= 1) pv += __shfl_xor(pv, m);   // 2 * sum(32 pts)

    if (lane == 0) bsum[w] = pv;
    __syncthreads();
    if (tid == 0) {
        float T = 0.0f;
        #pragma unroll
        for (int i = 0; i < 8; ++i) T += bsum[i];
        atomicAdd(out, T * (LAMBD / (2.0f * (float)N_POINTS)));
    }
}

extern "C" void kernel_launch(void* const* d_in, const int* in_sizes, int n_in,
                              void* d_out, int out_size, void* d_ws, size_t ws_size,
                              hipStream_t stream) {
    const float* x      = (const float*)d_in[0];
    const float* cent   = (const float*)d_in[1];
    const int*   alphap = (const int*)d_in[2];
    float* out = (float*)d_out;

    float*          c2_ws = (float*)d_ws;                          // 256 B
    unsigned short* afrag = (unsigned short*)((char*)d_ws + 256);  // 64 KiB

    hipLaunchKernelGGL(prep_kernel, dim3(N_CLUSTERS), dim3(64), 0, stream,
                       cent, c2_ws, afrag, out);
    hipLaunchKernelGGL(main_kernel, dim3(N_POINTS / PTS_PER_BLK), dim3(THREADS), 0, stream,
                       x, alphap, c2_ws, afrag, out);
}